// Round 1
// baseline (283.872 us; speedup 1.0000x reference)
//
#include <hip/hip_runtime.h>
#include <hip/hip_bf16.h>

constexpr int kT = 32768;   // tokens = B*N
constexpr int kD = 128;
constexpr int kH = 256;
constexpr int kE = 16;

typedef __bf16 bf16x8 __attribute__((ext_vector_type(8)));
typedef unsigned short u16x8 __attribute__((ext_vector_type(8)));
typedef float f32x4 __attribute__((ext_vector_type(4)));

#define LDX 136   // x-tile LDS row stride (ushort) = 128 + 8 pad (bank spread)
#define LDH 264   // h-tile LDS row stride (ushort) = 256 + 8 pad

__device__ __forceinline__ unsigned short f2bf(float f) {
  unsigned int u = __float_as_uint(f);
  u += 0x7FFFu + ((u >> 16) & 1u);   // round-to-nearest-even
  return (unsigned short)(u >> 16);
}

// ---------- prep: bf16 cast of x + transposed bf16 weights -----------------
__global__ __launch_bounds__(256) void prep_kernel(
    const float* __restrict__ x, const float* __restrict__ W1,
    const float* __restrict__ W2, const float* __restrict__ Wu1,
    const float* __restrict__ Wu2,
    unsigned short* __restrict__ xb, unsigned short* __restrict__ W1t,
    unsigned short* __restrict__ W2t, unsigned short* __restrict__ Wu1t,
    unsigned short* __restrict__ Wu2t)
{
  int idx = blockIdx.x * 256 + threadIdx.x;
  constexpr int RA = kT * kD / 8;    // 524288 (x, 8 elems/thread)
  constexpr int RB = kE * kH * kD;   // 524288
  constexpr int RC = kE * kD * kH;   // 524288
  constexpr int RD_ = kH * kD;       // 32768
  constexpr int RE_ = kD * kH;       // 32768
  if (idx < RA) {
    const float4* xf = reinterpret_cast<const float4*>(x) + (size_t)idx * 2;
    float4 f0 = xf[0], f1 = xf[1];
    u16x8 v;
    v[0] = f2bf(f0.x); v[1] = f2bf(f0.y); v[2] = f2bf(f0.z); v[3] = f2bf(f0.w);
    v[4] = f2bf(f1.x); v[5] = f2bf(f1.y); v[6] = f2bf(f1.z); v[7] = f2bf(f1.w);
    *reinterpret_cast<u16x8*>(xb + (size_t)idx * 8) = v;
    return;
  }
  idx -= RA;
  if (idx < RB) {                    // W1t[e][h][d] = W1[e][d][h]
    int e = idx >> 15, r = idx & 32767;
    int h = r >> 7, d = r & 127;
    W1t[RA * 0 + idx] = f2bf(W1[(e << 15) + d * kH + h]);
    return;
  }
  idx -= RB;
  if (idx < RC) {                    // W2t[e][d][h] = W2[e][h][d]
    int e = idx >> 15, r = idx & 32767;
    int d = r >> 8, h = r & 255;
    W2t[idx] = f2bf(W2[(e << 15) + h * kD + d]);
    return;
  }
  idx -= RC;
  if (idx < RD_) {                   // Wu1t[h][d] = Wu1[d][h]
    int h = idx >> 7, d = idx & 127;
    Wu1t[idx] = f2bf(Wu1[d * kH + h]);
    return;
  }
  idx -= RD_;
  if (idx < RE_) {                   // Wu2t[d][h] = Wu2[h][d]
    int d = idx >> 8, h = idx & 255;
    Wu2t[idx] = f2bf(Wu2[h * kD + d]);
  }
}

// ---------- gating: logits, top-2, softmax, bucket scatter -----------------
__global__ __launch_bounds__(256) void gate_kernel(
    const float* __restrict__ x, const float* __restrict__ Wg,
    const float* __restrict__ bg,
    float* __restrict__ omega, int* __restrict__ cnt,
    int* __restrict__ btok, float* __restrict__ bgate)
{
  __shared__ float sW[kD * kE];   // 8 KB, [d][e]
  __shared__ float sX[64][kD];    // 32 KB
  __shared__ float sL[64][kE];    // 4 KB
  int tid = threadIdx.x;
  int t0 = blockIdx.x * 64;
  for (int i = tid; i < kD * kE; i += 256) sW[i] = Wg[i];
  const float4* xv = reinterpret_cast<const float4*>(x + (size_t)t0 * kD);
  float4* sx4 = reinterpret_cast<float4*>(&sX[0][0]);
  for (int i = tid; i < 64 * kD / 4; i += 256) sx4[i] = xv[i];
  __syncthreads();
  int e = tid & 15;
  int tq = tid >> 4;
  for (int p = 0; p < 4; ++p) {
    int tt = p * 16 + tq;
    double acc = (double)bg[e];    // fp64 accumulate: minimize top-2 flip risk vs np ref
    for (int d = 0; d < kD; ++d)
      acc += (double)sX[tt][d] * (double)sW[d * kE + e];
    sL[tt][e] = (float)acc;
  }
  __syncthreads();
  if (tid < 64) {
    float v0 = -3.4e38f, v1 = -3.4e38f;
    int e0 = 0, e1 = 0;
    for (int i = 0; i < kE; ++i) {
      float v = sL[tid][i];
      if (v > v0) { v1 = v0; e1 = e0; v0 = v; e0 = i; }
      else if (v > v1) { v1 = v; e1 = i; }
    }
    float r = expf(v1 - v0);
    float g0 = 1.f / (1.f + r);
    float g1 = 1.f - g0;
    int t = t0 + tid;
    omega[t] = 1.f - g0;           // 1 - max(gate)
    int p0 = atomicAdd(&cnt[e0], 1);
    btok[e0 * kT + p0] = t; bgate[e0 * kT + p0] = g0;
    int p1 = atomicAdd(&cnt[e1], 1);
    btok[e1 * kT + p1] = t; bgate[e1 * kT + p1] = g1;
  }
}

// ---------- fused 64-token tile: h=relu(x*B1+b1); acc2 = h*B2 --------------
// B1 stored as [kH][kD] (K-contiguous), B2 as [kD][kH] (K-contiguous).
__device__ __forceinline__ void mlp_tile(
    const unsigned short* xs, unsigned short* hs,
    const unsigned short* __restrict__ Bw1,
    const unsigned short* __restrict__ Bw2,
    const float* __restrict__ bias1,
    int w, int l, f32x4 acc2[4][2])
{
  const int lr = l & 15, lg = l >> 4;
  const f32x4 z4 = {0.f, 0.f, 0.f, 0.f};
  f32x4 acc[4][4];
#pragma unroll
  for (int m = 0; m < 4; ++m)
#pragma unroll
    for (int n = 0; n < 4; ++n) acc[m][n] = z4;

#pragma unroll
  for (int kk = 0; kk < 4; ++kk) {           // K = 128 over D
    bf16x8 a[4], b[4];
#pragma unroll
    for (int m = 0; m < 4; ++m)
      a[m] = *reinterpret_cast<const bf16x8*>(xs + (m * 16 + lr) * LDX + kk * 32 + lg * 8);
#pragma unroll
    for (int n = 0; n < 4; ++n)
      b[n] = *reinterpret_cast<const bf16x8*>(
          Bw1 + (size_t)(w * 64 + n * 16 + lr) * kD + kk * 32 + lg * 8);
#pragma unroll
    for (int m = 0; m < 4; ++m)
#pragma unroll
      for (int n = 0; n < 4; ++n)
        acc[m][n] = __builtin_amdgcn_mfma_f32_16x16x32_bf16(a[m], b[n], acc[m][n], 0, 0, 0);
  }
  // bias + relu -> hs (bf16), C/D layout: col=lane&15, row=(lane>>4)*4+q
#pragma unroll
  for (int n = 0; n < 4; ++n) {
    const int h = w * 64 + n * 16 + lr;
    const float bs = bias1[h];
#pragma unroll
    for (int m = 0; m < 4; ++m)
#pragma unroll
      for (int q = 0; q < 4; ++q) {
        float v = acc[m][n][q] + bs;
        v = fmaxf(v, 0.f);
        hs[(m * 16 + lg * 4 + q) * LDH + h] = f2bf(v);
      }
  }
  __syncthreads();
#pragma unroll
  for (int m = 0; m < 4; ++m)
#pragma unroll
    for (int n = 0; n < 2; ++n) acc2[m][n] = z4;
#pragma unroll
  for (int kk = 0; kk < 8; ++kk) {           // K = 256 over H
    bf16x8 a[4], b[2];
#pragma unroll
    for (int m = 0; m < 4; ++m)
      a[m] = *reinterpret_cast<const bf16x8*>(hs + (m * 16 + lr) * LDH + kk * 32 + lg * 8);
#pragma unroll
    for (int n = 0; n < 2; ++n)
      b[n] = *reinterpret_cast<const bf16x8*>(
          Bw2 + (size_t)(w * 32 + n * 16 + lr) * kH + kk * 32 + lg * 8);
#pragma unroll
    for (int m = 0; m < 4; ++m)
#pragma unroll
      for (int n = 0; n < 2; ++n)
        acc2[m][n] = __builtin_amdgcn_mfma_f32_16x16x32_bf16(a[m], b[n], acc2[m][n], 0, 0, 0);
  }
}

// ---------- universal expert (dense over all tokens), writes out -----------
__global__ __launch_bounds__(256) void uni_kernel(
    const unsigned short* __restrict__ xb,
    const unsigned short* __restrict__ Wu1t,
    const unsigned short* __restrict__ Wu2t,
    const float* __restrict__ bu1, const float* __restrict__ bu2,
    const float* __restrict__ omega, float* __restrict__ out)
{
  __shared__ alignas(16) unsigned short xs[64 * LDX];
  __shared__ alignas(16) unsigned short hs[64 * LDH];
  int tid = threadIdx.x;
  int t0 = blockIdx.x * 64;
  for (int s = tid; s < 1024; s += 256) {     // 64 rows x 16 B/slot x 16 slots
    int r = s >> 4, c = (s & 15) * 8;
    *reinterpret_cast<uint4*>(&xs[r * LDX + c]) =
        *reinterpret_cast<const uint4*>(&xb[(size_t)(t0 + r) * kD + c]);
  }
  __syncthreads();
  int w = tid >> 6, l = tid & 63;
  f32x4 acc2[4][2];
  mlp_tile(xs, hs, Wu1t, Wu2t, bu1, w, l, acc2);
  int lr = l & 15, lg = l >> 4;
  float bu2v[2];
#pragma unroll
  for (int n = 0; n < 2; ++n) bu2v[n] = bu2[w * 32 + n * 16 + lr];
#pragma unroll
  for (int m = 0; m < 4; ++m)
#pragma unroll
    for (int q = 0; q < 4; ++q) {
      int t = t0 + m * 16 + lg * 4 + q;
      float om = omega[t];
#pragma unroll
      for (int n = 0; n < 2; ++n) {
        int d = w * 32 + n * 16 + lr;
        out[(size_t)t * kD + d] = om * (acc2[m][n][q] + bu2v[n]);
      }
    }
}

// ---------- routed experts: gather tile, fused MLP, gated atomic add -------
__global__ __launch_bounds__(256) void expert_kernel(
    const unsigned short* __restrict__ xb,
    const unsigned short* __restrict__ W1t,
    const unsigned short* __restrict__ W2t,
    const float* __restrict__ b1, const float* __restrict__ b2,
    const int* __restrict__ cnt, const int* __restrict__ btok,
    const float* __restrict__ bgate, float* __restrict__ out)
{
  __shared__ alignas(16) unsigned short xs[64 * LDX];
  __shared__ alignas(16) unsigned short hs[64 * LDH];
  __shared__ int toks[64];
  __shared__ float gts[64];
  int tid = threadIdx.x;
  // map blockIdx -> (expert, tile) by scanning counters (16 scalar loads)
  int e = -1, tile = 0;
  {
    int bsum = 0, b = blockIdx.x;
    for (int i = 0; i < kE; ++i) {
      int tl = (cnt[i] + 63) >> 6;
      if (b < bsum + tl) { e = i; tile = b - bsum; break; }
      bsum += tl;
    }
  }
  if (e < 0) return;
  int ce = cnt[e];
  int s0 = tile * 64;
  int rows = min(64, ce - s0);
  if (tid < 64) {
    if (tid < rows) {
      toks[tid] = btok[e * kT + s0 + tid];
      gts[tid]  = bgate[e * kT + s0 + tid];
    } else { toks[tid] = 0; gts[tid] = 0.f; }
  }
  __syncthreads();
  for (int s = tid; s < 1024; s += 256) {     // gather 64 token rows
    int r = s >> 4, c = (s & 15) * 8;
    uint4 v = make_uint4(0u, 0u, 0u, 0u);
    if (r < rows)
      v = *reinterpret_cast<const uint4*>(&xb[(size_t)toks[r] * kD + c]);
    *reinterpret_cast<uint4*>(&xs[r * LDX + c]) = v;
  }
  __syncthreads();
  int w = tid >> 6, l = tid & 63;
  f32x4 acc2[4][2];
  mlp_tile(xs, hs, W1t + (size_t)e * kH * kD, W2t + (size_t)e * kD * kH,
           b1 + e * kH, w, l, acc2);
  int lr = l & 15, lg = l >> 4;
  float b2v[2];
#pragma unroll
  for (int n = 0; n < 2; ++n) b2v[n] = b2[e * kD + w * 32 + n * 16 + lr];
#pragma unroll
  for (int m = 0; m < 4; ++m)
#pragma unroll
    for (int q = 0; q < 4; ++q) {
      int r = m * 16 + lg * 4 + q;
      if (r < rows) {
        int t = toks[r];
        float g = gts[r];
#pragma unroll
        for (int n = 0; n < 2; ++n) {
          int d = w * 32 + n * 16 + lr;
          unsafeAtomicAdd(&out[(size_t)t * kD + d], g * (acc2[m][n][q] + b2v[n]));
        }
      }
    }
}

// ---------- launch ---------------------------------------------------------
extern "C" void kernel_launch(void* const* d_in, const int* in_sizes, int n_in,
                              void* d_out, int out_size, void* d_ws, size_t ws_size,
                              hipStream_t stream) {
  (void)in_sizes; (void)n_in; (void)out_size; (void)ws_size;
  const float* x   = (const float*)d_in[0];
  const float* Wg  = (const float*)d_in[1];
  const float* bg  = (const float*)d_in[2];
  const float* W1  = (const float*)d_in[3];
  const float* b1  = (const float*)d_in[4];
  const float* W2  = (const float*)d_in[5];
  const float* b2  = (const float*)d_in[6];
  const float* Wu1 = (const float*)d_in[7];
  const float* bu1 = (const float*)d_in[8];
  const float* Wu2 = (const float*)d_in[9];
  const float* bu2 = (const float*)d_in[10];
  float* out = (float*)d_out;

  char* ws = (char*)d_ws;
  constexpr size_t OFF_XB    = 0;                       // 8388608 B
  constexpr size_t OFF_W1T   = 8388608;                 // 1048576
  constexpr size_t OFF_W2T   = 9437184;                 // 1048576
  constexpr size_t OFF_WU1T  = 10485760;                // 65536
  constexpr size_t OFF_WU2T  = 10551296;                // 65536
  constexpr size_t OFF_OM    = 10616832;                // 131072
  constexpr size_t OFF_CNT   = 10747904;                // 64 (pad 256)
  constexpr size_t OFF_BTOK  = 10748160;                // 2097152
  constexpr size_t OFF_BGATE = 12845312;                // 2097152 -> end 14942464

  unsigned short* xb    = (unsigned short*)(ws + OFF_XB);
  unsigned short* W1t   = (unsigned short*)(ws + OFF_W1T);
  unsigned short* W2t   = (unsigned short*)(ws + OFF_W2T);
  unsigned short* Wu1t  = (unsigned short*)(ws + OFF_WU1T);
  unsigned short* Wu2t  = (unsigned short*)(ws + OFF_WU2T);
  float* omega = (float*)(ws + OFF_OM);
  int*   cnt   = (int*)(ws + OFF_CNT);
  int*   btok  = (int*)(ws + OFF_BTOK);
  float* bgate = (float*)(ws + OFF_BGATE);

  hipMemsetAsync(cnt, 0, 64, stream);
  prep_kernel<<<6400, 256, 0, stream>>>(x, W1, W2, Wu1, Wu2, xb, W1t, W2t, Wu1t, Wu2t);
  gate_kernel<<<kT / 64, 256, 0, stream>>>(x, Wg, bg, omega, cnt, btok, bgate);
  uni_kernel<<<kT / 64, 256, 0, stream>>>(xb, Wu1t, Wu2t, bu1, bu2, omega, out);
  expert_kernel<<<1040, 256, 0, stream>>>(xb, W1t, W2t, b1, b2, cnt, btok, bgate, out);
}

// Round 2
// 99.721 us; speedup vs baseline: 2.8467x; 2.8467x over previous
//
#include <hip/hip_runtime.h>
#include <hip/hip_bf16.h>

constexpr int kT = 32768;   // tokens = B*N
constexpr int kD = 128;
constexpr int kH = 256;
constexpr int kE = 16;

typedef __bf16 bf16x8 __attribute__((ext_vector_type(8)));
typedef unsigned short u16x8 __attribute__((ext_vector_type(8)));
typedef float f32x4 __attribute__((ext_vector_type(4)));

#define LDX 136   // x-tile LDS row stride (ushort) = 128 + 8 pad
#define LDH 264   // h-tile LDS row stride (ushort) = 256 + 8 pad

// fused front-end block ranges
constexpr int NB_XCAST = 2048;            // x fp32 -> bf16, 8 elem/thread
constexpr int NB_TP    = 272;             // 64x64 transpose tiles (17 W1-like + 17 W2-like, 8 tiles each)
constexpr int NB_GATE  = kT / 64;         // 512
constexpr int CNT_STRIDE = 32;            // counters padded to 128 B (own cache line)

__device__ __forceinline__ unsigned short f2bf(float f) {
  unsigned int u = __float_as_uint(f);
  u += 0x7FFFu + ((u >> 16) & 1u);   // round-to-nearest-even
  return (unsigned short)(u >> 16);
}

// ---------- fused front-end: x cast | weight transpose | gating ------------
__global__ __launch_bounds__(256) void front_kernel(
    const float* __restrict__ x, const float* __restrict__ Wg,
    const float* __restrict__ bg,
    const float* __restrict__ W1, const float* __restrict__ W2,
    const float* __restrict__ Wu1, const float* __restrict__ Wu2,
    unsigned short* __restrict__ xb, unsigned short* __restrict__ W1t,
    unsigned short* __restrict__ W2t, unsigned short* __restrict__ Wu1t,
    unsigned short* __restrict__ Wu2t,
    float* __restrict__ omega, int* __restrict__ cnt,
    int* __restrict__ btok, float* __restrict__ bgate)
{
  __shared__ __align__(16) char smem[46848];
  const int tid = threadIdx.x;
  const int b = blockIdx.x;

  if (b < NB_XCAST) {
    // ---- x fp32 -> bf16, fully coalesced
    int idx = b * 256 + tid;
    const float4* xf = reinterpret_cast<const float4*>(x) + (size_t)idx * 2;
    float4 f0 = xf[0], f1 = xf[1];
    u16x8 v;
    v[0] = f2bf(f0.x); v[1] = f2bf(f0.y); v[2] = f2bf(f0.z); v[3] = f2bf(f0.w);
    v[4] = f2bf(f1.x); v[5] = f2bf(f1.y); v[6] = f2bf(f1.z); v[7] = f2bf(f1.w);
    *reinterpret_cast<u16x8*>(xb + (size_t)idx * 8) = v;
    return;
  }

  if (b < NB_XCAST + NB_TP) {
    // ---- LDS-tiled transpose fp32 [R][C] -> bf16 [C][R], 64x64 tiles
    int bb = b - NB_XCAST;
    const float* src; unsigned short* dst; int R, C, r0, c0;
    if (bb < 136) {                 // W1-like: [128][256] -> [256][128]
      int m = bb >> 3, t8 = bb & 7;
      R = 128; C = 256;
      src = (m < 16) ? W1 + (size_t)m * 32768 : Wu1;
      dst = (m < 16) ? W1t + (size_t)m * 32768 : Wu1t;
      r0 = (t8 & 1) * 64; c0 = (t8 >> 1) * 64;
    } else {                        // W2-like: [256][128] -> [128][256]
      bb -= 136;
      int m = bb >> 3, t8 = bb & 7;
      R = 256; C = 128;
      src = (m < 16) ? W2 + (size_t)m * 32768 : Wu2;
      dst = (m < 16) ? W2t + (size_t)m * 32768 : Wu2t;
      r0 = (t8 >> 1) * 64; c0 = (t8 & 1) * 64;
    }
    unsigned short (*tl)[72] = reinterpret_cast<unsigned short(*)[72]>(smem);
#pragma unroll
    for (int i = 0; i < 4; ++i) {   // coalesced float4 reads, transposed bf16 LDS writes
      int s = i * 256 + tid;
      int r = s >> 4, c4 = s & 15;
      float4 v = *reinterpret_cast<const float4*>(&src[(size_t)(r0 + r) * C + c0 + c4 * 4]);
      tl[c4 * 4 + 0][r] = f2bf(v.x);
      tl[c4 * 4 + 1][r] = f2bf(v.y);
      tl[c4 * 4 + 2][r] = f2bf(v.z);
      tl[c4 * 4 + 3][r] = f2bf(v.w);
    }
    __syncthreads();
#pragma unroll
    for (int i = 0; i < 2; ++i) {   // 16 B-vector coalesced stores
      int s = i * 256 + tid;
      int c = s >> 3, seg = s & 7;
      uint4 v = *reinterpret_cast<const uint4*>(&tl[c][seg * 8]);
      *reinterpret_cast<uint4*>(&dst[(size_t)(c0 + c) * R + r0 + seg * 8]) = v;
    }
    return;
  }

  // ---- gating: logits (fp64 accum), top-2, softmax, low-contention scatter
  {
    float* sWt = reinterpret_cast<float*>(smem);            // [16][132]
    float* sX  = reinterpret_cast<float*>(smem + 8448);     // [64][132]
    float* sL  = reinterpret_cast<float*>(smem + 42240);    // [64][17]
    int* hcnt  = reinterpret_cast<int*>(smem + 46592);      // [16]
    int* hbase = reinterpret_cast<int*>(smem + 46656);      // [16]
    const int t0 = (b - NB_XCAST - NB_TP) * 64;

    if (tid < kE) hcnt[tid] = 0;
    for (int i = tid; i < kD * kE; i += 256) {              // Wg[d][e] -> sWt[e][d]
      int d = i >> 4, e = i & 15;
      sWt[e * 132 + d] = Wg[i];
    }
    const float4* xv = reinterpret_cast<const float4*>(x + (size_t)t0 * kD);
    for (int i = tid; i < 64 * kD / 4; i += 256) {
      int r = i >> 5, c4 = i & 31;
      *reinterpret_cast<float4*>(&sX[r * 132 + c4 * 4]) = xv[i];
    }
    __syncthreads();

    const int e = tid & 15, tq = tid >> 4;
    const double bgd = (double)bg[e];
    const float4* wr = reinterpret_cast<const float4*>(&sWt[e * 132]);
#pragma unroll
    for (int p = 0; p < 4; ++p) {
      int tt = p * 16 + tq;
      const float4* xr = reinterpret_cast<const float4*>(&sX[tt * 132]);
      double acc = bgd;
#pragma unroll
      for (int d4 = 0; d4 < 32; ++d4) {
        float4 xa = xr[d4], wa = wr[d4];
        acc += (double)xa.x * (double)wa.x;
        acc += (double)xa.y * (double)wa.y;
        acc += (double)xa.z * (double)wa.z;
        acc += (double)xa.w * (double)wa.w;
      }
      sL[tt * 17 + e] = (float)acc;
    }
    __syncthreads();

    int e0 = 0, e1 = 0, lp0 = 0, lp1 = 0;
    float g0 = 0.f, g1 = 0.f;
    const int t = t0 + tid;
    if (tid < 64) {
      float v0 = -3.4e38f, v1 = -3.4e38f;
      for (int i = 0; i < kE; ++i) {
        float v = sL[tid * 17 + i];
        if (v > v0) { v1 = v0; e1 = e0; v0 = v; e0 = i; }
        else if (v > v1) { v1 = v; e1 = i; }
      }
      float r = expf(v1 - v0);
      g0 = 1.f / (1.f + r);
      g1 = 1.f - g0;
      omega[t] = 1.f - g0;
      lp0 = atomicAdd(&hcnt[e0], 1);   // LDS atomics: local positions
      lp1 = atomicAdd(&hcnt[e1], 1);
    }
    __syncthreads();
    if (tid < kE)                      // ONE global atomic per (block, expert), padded lines
      hbase[tid] = atomicAdd(&cnt[tid * CNT_STRIDE], hcnt[tid]);
    __syncthreads();
    if (tid < 64) {
      int p0 = hbase[e0] + lp0;
      btok[e0 * kT + p0] = t; bgate[e0 * kT + p0] = g0;
      int p1 = hbase[e1] + lp1;
      btok[e1 * kT + p1] = t; bgate[e1 * kT + p1] = g1;
    }
  }
}

// ---------- fused 64-token tile: h=relu(x*B1+b1); acc2 = h*B2 --------------
// B1 stored as [kH][kD] (K-contiguous), B2 as [kD][kH] (K-contiguous).
__device__ __forceinline__ void mlp_tile(
    const unsigned short* xs, unsigned short* hs,
    const unsigned short* __restrict__ Bw1,
    const unsigned short* __restrict__ Bw2,
    const float* __restrict__ bias1,
    int w, int l, f32x4 acc2[4][2])
{
  const int lr = l & 15, lg = l >> 4;
  const f32x4 z4 = {0.f, 0.f, 0.f, 0.f};
  f32x4 acc[4][4];
#pragma unroll
  for (int m = 0; m < 4; ++m)
#pragma unroll
    for (int n = 0; n < 4; ++n) acc[m][n] = z4;

#pragma unroll
  for (int kk = 0; kk < 4; ++kk) {           // K = 128 over D
    bf16x8 a[4], bfr[4];
#pragma unroll
    for (int m = 0; m < 4; ++m)
      a[m] = *reinterpret_cast<const bf16x8*>(xs + (m * 16 + lr) * LDX + kk * 32 + lg * 8);
#pragma unroll
    for (int n = 0; n < 4; ++n)
      bfr[n] = *reinterpret_cast<const bf16x8*>(
          Bw1 + (size_t)(w * 64 + n * 16 + lr) * kD + kk * 32 + lg * 8);
#pragma unroll
    for (int m = 0; m < 4; ++m)
#pragma unroll
      for (int n = 0; n < 4; ++n)
        acc[m][n] = __builtin_amdgcn_mfma_f32_16x16x32_bf16(a[m], bfr[n], acc[m][n], 0, 0, 0);
  }
  // bias + relu -> hs (bf16), C/D layout: col=lane&15, row=(lane>>4)*4+q
#pragma unroll
  for (int n = 0; n < 4; ++n) {
    const int h = w * 64 + n * 16 + lr;
    const float bs = bias1[h];
#pragma unroll
    for (int m = 0; m < 4; ++m)
#pragma unroll
      for (int q = 0; q < 4; ++q) {
        float v = acc[m][n][q] + bs;
        v = fmaxf(v, 0.f);
        hs[(m * 16 + lg * 4 + q) * LDH + h] = f2bf(v);
      }
  }
  __syncthreads();
#pragma unroll
  for (int m = 0; m < 4; ++m)
#pragma unroll
    for (int n = 0; n < 2; ++n) acc2[m][n] = z4;
#pragma unroll
  for (int kk = 0; kk < 8; ++kk) {           // K = 256 over H
    bf16x8 a[4], bfr[2];
#pragma unroll
    for (int m = 0; m < 4; ++m)
      a[m] = *reinterpret_cast<const bf16x8*>(hs + (m * 16 + lr) * LDH + kk * 32 + lg * 8);
#pragma unroll
    for (int n = 0; n < 2; ++n)
      bfr[n] = *reinterpret_cast<const bf16x8*>(
          Bw2 + (size_t)(w * 32 + n * 16 + lr) * kH + kk * 32 + lg * 8);
#pragma unroll
    for (int m = 0; m < 4; ++m)
#pragma unroll
      for (int n = 0; n < 2; ++n)
        acc2[m][n] = __builtin_amdgcn_mfma_f32_16x16x32_bf16(a[m], bfr[n], acc2[m][n], 0, 0, 0);
  }
}

// ---------- universal expert (dense over all tokens), writes out -----------
__global__ __launch_bounds__(256) void uni_kernel(
    const unsigned short* __restrict__ xb,
    const unsigned short* __restrict__ Wu1t,
    const unsigned short* __restrict__ Wu2t,
    const float* __restrict__ bu1, const float* __restrict__ bu2,
    const float* __restrict__ omega, float* __restrict__ out)
{
  __shared__ alignas(16) unsigned short xs[64 * LDX];
  __shared__ alignas(16) unsigned short hs[64 * LDH];
  int tid = threadIdx.x;
  int t0 = blockIdx.x * 64;
  for (int s = tid; s < 1024; s += 256) {
    int r = s >> 4, c = (s & 15) * 8;
    *reinterpret_cast<uint4*>(&xs[r * LDX + c]) =
        *reinterpret_cast<const uint4*>(&xb[(size_t)(t0 + r) * kD + c]);
  }
  __syncthreads();
  int w = tid >> 6, l = tid & 63;
  f32x4 acc2[4][2];
  mlp_tile(xs, hs, Wu1t, Wu2t, bu1, w, l, acc2);
  int lr = l & 15, lg = l >> 4;
  float bu2v[2];
#pragma unroll
  for (int n = 0; n < 2; ++n) bu2v[n] = bu2[w * 32 + n * 16 + lr];
#pragma unroll
  for (int m = 0; m < 4; ++m)
#pragma unroll
    for (int q = 0; q < 4; ++q) {
      int t = t0 + m * 16 + lg * 4 + q;
      float om = omega[t];
#pragma unroll
      for (int n = 0; n < 2; ++n) {
        int d = w * 32 + n * 16 + lr;
        out[(size_t)t * kD + d] = om * (acc2[m][n][q] + bu2v[n]);
      }
    }
}

// ---------- routed experts: gather tile, fused MLP, gated atomic add -------
__global__ __launch_bounds__(256) void expert_kernel(
    const unsigned short* __restrict__ xb,
    const unsigned short* __restrict__ W1t,
    const unsigned short* __restrict__ W2t,
    const float* __restrict__ b1, const float* __restrict__ b2,
    const int* __restrict__ cnt, const int* __restrict__ btok,
    const float* __restrict__ bgate, float* __restrict__ out)
{
  __shared__ alignas(16) unsigned short xs[64 * LDX];
  __shared__ alignas(16) unsigned short hs[64 * LDH];
  __shared__ int toks[64];
  __shared__ float gts[64];
  int tid = threadIdx.x;
  int e = -1, tile = 0;
  {
    int bsum = 0, b = blockIdx.x;
    for (int i = 0; i < kE; ++i) {
      int tl = (cnt[i * CNT_STRIDE] + 63) >> 6;
      if (b < bsum + tl) { e = i; tile = b - bsum; break; }
      bsum += tl;
    }
  }
  if (e < 0) return;
  int ce = cnt[e * CNT_STRIDE];
  int s0 = tile * 64;
  int rows = min(64, ce - s0);
  if (tid < 64) {
    if (tid < rows) {
      toks[tid] = btok[e * kT + s0 + tid];
      gts[tid]  = bgate[e * kT + s0 + tid];
    } else { toks[tid] = 0; gts[tid] = 0.f; }
  }
  __syncthreads();
  for (int s = tid; s < 1024; s += 256) {
    int r = s >> 4, c = (s & 15) * 8;
    uint4 v = make_uint4(0u, 0u, 0u, 0u);
    if (r < rows)
      v = *reinterpret_cast<const uint4*>(&xb[(size_t)toks[r] * kD + c]);
    *reinterpret_cast<uint4*>(&xs[r * LDX + c]) = v;
  }
  __syncthreads();
  int w = tid >> 6, l = tid & 63;
  f32x4 acc2[4][2];
  mlp_tile(xs, hs, W1t + (size_t)e * kH * kD, W2t + (size_t)e * kD * kH,
           b1 + e * kH, w, l, acc2);
  int lr = l & 15, lg = l >> 4;
  float b2v[2];
#pragma unroll
  for (int n = 0; n < 2; ++n) b2v[n] = b2[e * kD + w * 32 + n * 16 + lr];
#pragma unroll
  for (int m = 0; m < 4; ++m)
#pragma unroll
    for (int q = 0; q < 4; ++q) {
      int r = m * 16 + lg * 4 + q;
      if (r < rows) {
        int t = toks[r];
        float g = gts[r];
#pragma unroll
        for (int n = 0; n < 2; ++n) {
          int d = w * 32 + n * 16 + lr;
          unsafeAtomicAdd(&out[(size_t)t * kD + d], g * (acc2[m][n][q] + b2v[n]));
        }
      }
    }
}

// ---------- launch ---------------------------------------------------------
extern "C" void kernel_launch(void* const* d_in, const int* in_sizes, int n_in,
                              void* d_out, int out_size, void* d_ws, size_t ws_size,
                              hipStream_t stream) {
  (void)in_sizes; (void)n_in; (void)out_size; (void)ws_size;
  const float* x   = (const float*)d_in[0];
  const float* Wg  = (const float*)d_in[1];
  const float* bg  = (const float*)d_in[2];
  const float* W1  = (const float*)d_in[3];
  const float* b1  = (const float*)d_in[4];
  const float* W2  = (const float*)d_in[5];
  const float* b2  = (const float*)d_in[6];
  const float* Wu1 = (const float*)d_in[7];
  const float* bu1 = (const float*)d_in[8];
  const float* Wu2 = (const float*)d_in[9];
  const float* bu2 = (const float*)d_in[10];
  float* out = (float*)d_out;

  char* ws = (char*)d_ws;
  constexpr size_t OFF_XB    = 0;                       // 8388608 B
  constexpr size_t OFF_W1T   = 8388608;                 // 1048576
  constexpr size_t OFF_W2T   = 9437184;                 // 1048576
  constexpr size_t OFF_WU1T  = 10485760;                // 65536
  constexpr size_t OFF_WU2T  = 10551296;                // 65536
  constexpr size_t OFF_OM    = 10616832;                // 131072
  constexpr size_t OFF_CNT   = 10747904;                // 16*32*4 = 2048
  constexpr size_t OFF_BTOK  = 10749952;                // 2097152
  constexpr size_t OFF_BGATE = 12847104;                // 2097152 -> end 14944256

  unsigned short* xb    = (unsigned short*)(ws + OFF_XB);
  unsigned short* W1t   = (unsigned short*)(ws + OFF_W1T);
  unsigned short* W2t   = (unsigned short*)(ws + OFF_W2T);
  unsigned short* Wu1t  = (unsigned short*)(ws + OFF_WU1T);
  unsigned short* Wu2t  = (unsigned short*)(ws + OFF_WU2T);
  float* omega = (float*)(ws + OFF_OM);
  int*   cnt   = (int*)(ws + OFF_CNT);
  int*   btok  = (int*)(ws + OFF_BTOK);
  float* bgate = (float*)(ws + OFF_BGATE);

  hipMemsetAsync(cnt, 0, kE * CNT_STRIDE * sizeof(int), stream);
  front_kernel<<<NB_XCAST + NB_TP + NB_GATE, 256, 0, stream>>>(
      x, Wg, bg, W1, W2, Wu1, Wu2,
      xb, W1t, W2t, Wu1t, Wu2t, omega, cnt, btok, bgate);
  uni_kernel<<<kT / 64, 256, 0, stream>>>(xb, Wu1t, Wu2t, bu1, bu2, omega, out);
  expert_kernel<<<1040, 256, 0, stream>>>(xb, W1t, W2t, b1, b2, cnt, btok, bgate, out);
}